// Round 1
// baseline (737.863 us; speedup 1.0000x reference)
//
#include <hip/hip_runtime.h>
#include <hip/hip_bf16.h>

// QuantizedLinear: y[t,o] = scale * sum_i x[t,i]*W[o,i] + bias[o]
// M=TOKENS=8192, N=D_OUT=4096, K=D_IN=4096 (all divisible by tile dims).
//
// Round 0: bf16 MFMA GEMM, 128x128 tile, BK=32, fp32->bf16 conversion fused
// into the LDS staging phase. W codes (0..126) are exact in bf16; x rounds
// RNE (error << threshold).

typedef __bf16 bf16_t;
typedef __attribute__((ext_vector_type(8))) __bf16 bf16x8;
typedef __attribute__((ext_vector_type(4))) __bf16 bf16x4;
typedef __attribute__((ext_vector_type(4))) float f32x4;

#define BM 128
#define BN 128
#define BK 32

__global__ __launch_bounds__(256)
void ql_gemm_bf16(const float* __restrict__ X,      // [M,K]
                  const float* __restrict__ W,      // [N,K]
                  const float* __restrict__ bias,   // [N]
                  const float* __restrict__ scale_p,// [1]
                  float* __restrict__ Y,            // [M,N]
                  int M, int N, int K)
{
    __shared__ alignas(16) bf16_t lA[BM][BK];
    __shared__ alignas(16) bf16_t lB[BN][BK];

    const int tid  = threadIdx.x;
    const int lane = tid & 63;
    const int wave = tid >> 6;            // 0..3
    const int wm   = (wave & 1) * 64;     // wave M-offset within tile
    const int wn   = (wave >> 1) * 64;    // wave N-offset within tile

    const int m0 = blockIdx.x * BM;       // token-tile base
    const int n0 = blockIdx.y * BN;       // out-feature-tile base

    const int r_lane = lane & 15;
    const int quad   = lane >> 4;

    f32x4 acc[4][4];
#pragma unroll
    for (int i = 0; i < 4; i++)
#pragma unroll
        for (int j = 0; j < 4; j++)
            acc[i][j] = (f32x4)0.0f;

    for (int k0 = 0; k0 < K; k0 += BK) {
        // ---- stage: 128x32 fp32 of X and W -> bf16 LDS ----
        // 1024 float4 per matrix; 256 threads x 4 iters.
        // l = tid + i*256; row = l>>3 (8 float4/row), col4 = (l&7)*4
#pragma unroll
        for (int i = 0; i < 4; i++) {
            const int l   = tid + i * 256;
            const int row = l >> 3;
            const int c4  = (l & 7) * 4;
            const float4 xa = *(const float4*)(X + (size_t)(m0 + row) * K + k0 + c4);
            const float4 wb = *(const float4*)(W + (size_t)(n0 + row) * K + k0 + c4);
            bf16x4 xh = { (bf16_t)xa.x, (bf16_t)xa.y, (bf16_t)xa.z, (bf16_t)xa.w };
            bf16x4 wh = { (bf16_t)wb.x, (bf16_t)wb.y, (bf16_t)wb.z, (bf16_t)wb.w };
            *(bf16x4*)&lA[row][c4] = xh;
            *(bf16x4*)&lB[row][c4] = wh;
        }
        __syncthreads();

        // ---- LDS -> fragments: contiguous 8-bf16 K-runs, ds_read_b128 ----
        bf16x8 af[4], bfr[4];
#pragma unroll
        for (int i = 0; i < 4; i++) {
            af[i]  = *(const bf16x8*)&lA[wm + i * 16 + r_lane][quad * 8];
            bfr[i] = *(const bf16x8*)&lB[wn + i * 16 + r_lane][quad * 8];
        }

        // ---- 16 MFMAs: acc[i][j] += A_i * B_j ----
#pragma unroll
        for (int i = 0; i < 4; i++)
#pragma unroll
            for (int j = 0; j < 4; j++)
                acc[i][j] = __builtin_amdgcn_mfma_f32_16x16x32_bf16(
                    af[i], bfr[j], acc[i][j], 0, 0, 0);

        __syncthreads();
    }

    // ---- epilogue: y = acc*scale + bias ----
    // C/D layout: col = lane&15 (N index), row = quad*4 + reg (M index)
    const float s = *scale_p;
#pragma unroll
    for (int j = 0; j < 4; j++) {
        const int col  = n0 + wn + j * 16 + r_lane;
        const float bc = bias[col];
#pragma unroll
        for (int i = 0; i < 4; i++) {
            const int rowg = m0 + wm + i * 16 + quad * 4;
#pragma unroll
            for (int r = 0; r < 4; r++) {
                Y[(size_t)(rowg + r) * N + col] = acc[i][j][r] * s + bc;
            }
        }
    }
}

extern "C" void kernel_launch(void* const* d_in, const int* in_sizes, int n_in,
                              void* d_out, int out_size, void* d_ws, size_t ws_size,
                              hipStream_t stream) {
    const float* X     = (const float*)d_in[0];  // [M,K]
    const float* W     = (const float*)d_in[1];  // [N,K]
    const float* bias  = (const float*)d_in[2];  // [N]
    const float* scale = (const float*)d_in[3];  // [1]
    float* Y           = (float*)d_out;

    const int N = in_sizes[2];             // D_OUT
    const int K = in_sizes[1] / N;         // D_IN
    const int M = in_sizes[0] / K;         // TOKENS

    dim3 grid(M / BM, N / BN);
    dim3 block(256);
    ql_gemm_bf16<<<grid, block, 0, stream>>>(X, W, bias, scale, Y, M, N, K);
}

// Round 2
// 634.653 us; speedup vs baseline: 1.1626x; 1.1626x over previous
//
#include <hip/hip_runtime.h>
#include <hip/hip_bf16.h>

// QuantizedLinear: y[t,o] = scale * sum_i x[t,i]*W[o,i] + bias[o]
// M=8192 (tokens), N=4096 (d_out), K=4096 (d_in).
//
// Round 2: two-phase. (1) fp32->bf16 convert of X,W into d_ws (~65us at HBM
// BW). (2) m97-style MFMA GEMM: 128x128 tile, BK=32, global->LDS staging via
// __builtin_amdgcn_global_load_lds width=16 (no VGPR round-trip, no cvt in
// the K-loop). Fallback to round-0 fused-convert staging if ws too small.

typedef __bf16 bf16_t;
typedef __attribute__((ext_vector_type(8))) __bf16 bf16x8;
typedef __attribute__((ext_vector_type(4))) __bf16 bf16x4;
typedef __attribute__((ext_vector_type(4))) float f32x4;

#define BM 128
#define BN 128
#define BK 32

// ---------------- phase 1: fp32 -> bf16 convert ----------------
__global__ __launch_bounds__(256)
void cvt_f32_bf16(const float* __restrict__ src, bf16_t* __restrict__ dst, int n8)
{
    // each thread: 8 floats (2x float4 load) -> 1x 16B store
    int i = blockIdx.x * 256 + threadIdx.x;
    if (i >= n8) return;
    const float4* s4 = (const float4*)(src) + (size_t)i * 2;
    float4 a = s4[0];
    float4 b = s4[1];
    bf16x8 o = { (bf16_t)a.x, (bf16_t)a.y, (bf16_t)a.z, (bf16_t)a.w,
                 (bf16_t)b.x, (bf16_t)b.y, (bf16_t)b.z, (bf16_t)b.w };
    *((bf16x8*)dst + i) = o;
}

// ---------------- phase 2: bf16 MFMA GEMM with global_load_lds ----------------
#define LDS_U32(p) ((__attribute__((address_space(3))) uint32_t*)(p))
#define GLB_U32(p) ((const __attribute__((address_space(1))) uint32_t*)(p))

__global__ __launch_bounds__(256)
void ql_gemm_bf16_dma(const bf16_t* __restrict__ X,   // [M,K] bf16
                      const bf16_t* __restrict__ W,   // [N,K] bf16
                      const float* __restrict__ bias, // [N]
                      const float* __restrict__ scale_p,
                      float* __restrict__ Y,          // [M,N]
                      int M, int N, int K)
{
    __shared__ alignas(16) bf16_t lA[BM][BK];
    __shared__ alignas(16) bf16_t lB[BN][BK];

    const int tid  = threadIdx.x;
    const int lane = tid & 63;
    const int wave = tid >> 6;            // 0..3
    const int wm   = (wave & 1) * 64;
    const int wn   = (wave >> 1) * 64;

    const int m0 = blockIdx.x * BM;
    const int n0 = blockIdx.y * BN;

    const int r_lane = lane & 15;
    const int quad   = lane >> 4;

    // global_load_lds addressing: per chunk c (16 rows of 32 bf16 = 1KB),
    // lane supplies 16B from row = c*16 + lane/4, col = (lane&3)*8.
    const int st_row = lane >> 2;         // 0..15 within chunk
    const int st_col = (lane & 3) * 8;    // bf16 col

    f32x4 acc[4][4];
#pragma unroll
    for (int i = 0; i < 4; i++)
#pragma unroll
        for (int j = 0; j < 4; j++)
            acc[i][j] = (f32x4)0.0f;

    for (int k0 = 0; k0 < K; k0 += BK) {
        // ---- stage via DMA: 8 chunks per matrix, 2 per wave ----
#pragma unroll
        for (int i = 0; i < 2; i++) {
            const int c   = i * 4 + wave;       // chunk 0..7
            const int row = c * 16 + st_row;
            __builtin_amdgcn_global_load_lds(
                GLB_U32(X + (size_t)(m0 + row) * K + k0 + st_col),
                LDS_U32(&lA[c * 16][0]), 16, 0, 0);
            __builtin_amdgcn_global_load_lds(
                GLB_U32(W + (size_t)(n0 + row) * K + k0 + st_col),
                LDS_U32(&lB[c * 16][0]), 16, 0, 0);
        }
        __syncthreads();

        // ---- LDS -> fragments (ds_read_b128) ----
        bf16x8 af[4], bfr[4];
#pragma unroll
        for (int i = 0; i < 4; i++) {
            af[i]  = *(const bf16x8*)&lA[wm + i * 16 + r_lane][quad * 8];
            bfr[i] = *(const bf16x8*)&lB[wn + i * 16 + r_lane][quad * 8];
        }

#pragma unroll
        for (int i = 0; i < 4; i++)
#pragma unroll
            for (int j = 0; j < 4; j++)
                acc[i][j] = __builtin_amdgcn_mfma_f32_16x16x32_bf16(
                    af[i], bfr[j], acc[i][j], 0, 0, 0);

        __syncthreads();
    }

    const float s = *scale_p;
#pragma unroll
    for (int j = 0; j < 4; j++) {
        const int col  = n0 + wn + j * 16 + r_lane;
        const float bc = bias[col];
#pragma unroll
        for (int i = 0; i < 4; i++) {
            const int rowg = m0 + wm + i * 16 + quad * 4;
#pragma unroll
            for (int r = 0; r < 4; r++)
                Y[(size_t)(rowg + r) * N + col] = acc[i][j][r] * s + bc;
        }
    }
}

// ---------------- fallback: round-0 fused-convert kernel ----------------
__global__ __launch_bounds__(256)
void ql_gemm_bf16_fused(const float* __restrict__ X, const float* __restrict__ W,
                        const float* __restrict__ bias, const float* __restrict__ scale_p,
                        float* __restrict__ Y, int M, int N, int K)
{
    __shared__ alignas(16) bf16_t lA[BM][BK];
    __shared__ alignas(16) bf16_t lB[BN][BK];

    const int tid  = threadIdx.x;
    const int lane = tid & 63;
    const int wave = tid >> 6;
    const int wm   = (wave & 1) * 64;
    const int wn   = (wave >> 1) * 64;
    const int m0 = blockIdx.x * BM;
    const int n0 = blockIdx.y * BN;
    const int r_lane = lane & 15;
    const int quad   = lane >> 4;

    f32x4 acc[4][4];
#pragma unroll
    for (int i = 0; i < 4; i++)
#pragma unroll
        for (int j = 0; j < 4; j++) acc[i][j] = (f32x4)0.0f;

    for (int k0 = 0; k0 < K; k0 += BK) {
#pragma unroll
        for (int i = 0; i < 4; i++) {
            const int l   = tid + i * 256;
            const int row = l >> 3;
            const int c4  = (l & 7) * 4;
            const float4 xa = *(const float4*)(X + (size_t)(m0 + row) * K + k0 + c4);
            const float4 wb = *(const float4*)(W + (size_t)(n0 + row) * K + k0 + c4);
            bf16x4 xh = { (bf16_t)xa.x, (bf16_t)xa.y, (bf16_t)xa.z, (bf16_t)xa.w };
            bf16x4 wh = { (bf16_t)wb.x, (bf16_t)wb.y, (bf16_t)wb.z, (bf16_t)wb.w };
            *(bf16x4*)&lA[row][c4] = xh;
            *(bf16x4*)&lB[row][c4] = wh;
        }
        __syncthreads();
        bf16x8 af[4], bfr[4];
#pragma unroll
        for (int i = 0; i < 4; i++) {
            af[i]  = *(const bf16x8*)&lA[wm + i * 16 + r_lane][quad * 8];
            bfr[i] = *(const bf16x8*)&lB[wn + i * 16 + r_lane][quad * 8];
        }
#pragma unroll
        for (int i = 0; i < 4; i++)
#pragma unroll
            for (int j = 0; j < 4; j++)
                acc[i][j] = __builtin_amdgcn_mfma_f32_16x16x32_bf16(af[i], bfr[j], acc[i][j], 0, 0, 0);
        __syncthreads();
    }

    const float s = *scale_p;
#pragma unroll
    for (int j = 0; j < 4; j++) {
        const int col  = n0 + wn + j * 16 + r_lane;
        const float bc = bias[col];
#pragma unroll
        for (int i = 0; i < 4; i++) {
            const int rowg = m0 + wm + i * 16 + quad * 4;
#pragma unroll
            for (int r = 0; r < 4; r++)
                Y[(size_t)(rowg + r) * N + col] = acc[i][j][r] * s + bc;
        }
    }
}

extern "C" void kernel_launch(void* const* d_in, const int* in_sizes, int n_in,
                              void* d_out, int out_size, void* d_ws, size_t ws_size,
                              hipStream_t stream) {
    const float* X     = (const float*)d_in[0];
    const float* W     = (const float*)d_in[1];
    const float* bias  = (const float*)d_in[2];
    const float* scale = (const float*)d_in[3];
    float* Y           = (float*)d_out;

    const int N = in_sizes[2];
    const int K = in_sizes[1] / N;
    const int M = in_sizes[0] / K;

    const size_t x_elems = (size_t)M * K;
    const size_t w_elems = (size_t)N * K;
    const size_t need = (x_elems + w_elems) * sizeof(bf16_t);

    dim3 grid(M / BM, N / BN);
    dim3 block(256);

    if (ws_size >= need) {
        bf16_t* Xb = (bf16_t*)d_ws;
        bf16_t* Wb = Xb + x_elems;
        int xn8 = (int)(x_elems / 8);
        int wn8 = (int)(w_elems / 8);
        cvt_f32_bf16<<<(xn8 + 255) / 256, 256, 0, stream>>>(X, Xb, xn8);
        cvt_f32_bf16<<<(wn8 + 255) / 256, 256, 0, stream>>>(W, Wb, wn8);
        ql_gemm_bf16_dma<<<grid, block, 0, stream>>>(Xb, Wb, bias, scale, Y, M, N, K);
    } else {
        ql_gemm_bf16_fused<<<grid, block, 0, stream>>>(X, W, bias, scale, Y, M, N, K);
    }
}

// Round 3
// 612.539 us; speedup vs baseline: 1.2046x; 1.0361x over previous
//
#include <hip/hip_runtime.h>
#include <hip/hip_bf16.h>

// QuantizedLinear: y[t,o] = scale * sum_i x[t,i]*W[o,i] + bias[o]
// M=8192 (tokens), N=4096 (d_out), K=4096 (d_in).
//
// Round 3:
//  (a) single fused fp32->bf16 convert kernel (float4 load -> bf16x4 store).
//  (b) GEMM: XOR-swizzled LDS layout. col-group g of row r lives at slot
//      g ^ ((r>>1)&3), so ds_read_b128 fragment reads are 2-way max (free).
//      DMA writers permute their *global source* column instead (keeps the
//      contiguous wave-uniform LDS destination global_load_lds requires).

typedef __bf16 bf16_t;
typedef __attribute__((ext_vector_type(8))) __bf16 bf16x8;
typedef __attribute__((ext_vector_type(4))) __bf16 bf16x4;
typedef __attribute__((ext_vector_type(4))) float f32x4;

#define BM 128
#define BN 128
#define BK 32

// ---------------- phase 1: fp32 -> bf16 convert (both X and W) -------------
__global__ __launch_bounds__(256)
void cvt2_f32_bf16(const float* __restrict__ xsrc, bf16_t* __restrict__ xdst, long xn4,
                   const float* __restrict__ wsrc, bf16_t* __restrict__ wdst, long wn4)
{
    long i = (long)blockIdx.x * 256 + threadIdx.x;   // float4 index
    const float4* s;
    bf16x4* d;
    if (i < xn4) {
        s = (const float4*)xsrc; d = (bf16x4*)xdst;
    } else {
        i -= xn4;
        if (i >= wn4) return;
        s = (const float4*)wsrc; d = (bf16x4*)wdst;
    }
    float4 a = s[i];
    bf16x4 o = { (bf16_t)a.x, (bf16_t)a.y, (bf16_t)a.z, (bf16_t)a.w };
    d[i] = o;
}

// ---------------- phase 2: bf16 MFMA GEMM, DMA staging, swizzled LDS -------
#define LDS_U32(p) ((__attribute__((address_space(3))) uint32_t*)(p))
#define GLB_U32(p) ((const __attribute__((address_space(1))) uint32_t*)(p))

__global__ __launch_bounds__(256)
void ql_gemm_bf16_dma(const bf16_t* __restrict__ X,   // [M,K] bf16
                      const bf16_t* __restrict__ W,   // [N,K] bf16
                      const float* __restrict__ bias, // [N]
                      const float* __restrict__ scale_p,
                      float* __restrict__ Y,          // [M,N]
                      int M, int N, int K)
{
    __shared__ alignas(16) bf16_t lA[BM][BK];
    __shared__ alignas(16) bf16_t lB[BN][BK];

    const int tid  = threadIdx.x;
    const int lane = tid & 63;
    const int wave = tid >> 6;            // 0..3
    const int wm   = (wave & 1) * 64;
    const int wn   = (wave >> 1) * 64;

    const int m0 = blockIdx.x * BM;
    const int n0 = blockIdx.y * BN;

    const int r_lane = lane & 15;
    const int quad   = lane >> 4;

    // DMA staging: chunk c = 16 rows x 32 bf16 = 1KB contiguous LDS.
    // lane's LDS slot: row = c*16 + (lane>>2), slot-group = lane&3.
    // Swizzle: slot-group g' holds data col-group q = g' ^ ((row>>1)&3).
    const int st_row = lane >> 2;                       // 0..15 within chunk
    const int st_q   = (lane & 3) ^ ((lane >> 3) & 3);  // source col group
    const int st_col = st_q * 8;                        // bf16 col in global

    // Fragment reads: want col-group `quad` of row (base + r_lane);
    // it lives at slot-group quad ^ ((r_lane>>1)&3). Loop-invariant.
    const int rd_col = (quad ^ ((r_lane >> 1) & 3)) * 8;

    f32x4 acc[4][4];
#pragma unroll
    for (int i = 0; i < 4; i++)
#pragma unroll
        for (int j = 0; j < 4; j++)
            acc[i][j] = (f32x4)0.0f;

    for (int k0 = 0; k0 < K; k0 += BK) {
#pragma unroll
        for (int i = 0; i < 2; i++) {
            const int c   = i * 4 + wave;       // chunk 0..7
            const int row = c * 16 + st_row;
            __builtin_amdgcn_global_load_lds(
                GLB_U32(X + (size_t)(m0 + row) * K + k0 + st_col),
                LDS_U32(&lA[c * 16][0]), 16, 0, 0);
            __builtin_amdgcn_global_load_lds(
                GLB_U32(W + (size_t)(n0 + row) * K + k0 + st_col),
                LDS_U32(&lB[c * 16][0]), 16, 0, 0);
        }
        __syncthreads();

        bf16x8 af[4], bfr[4];
#pragma unroll
        for (int i = 0; i < 4; i++) {
            af[i]  = *(const bf16x8*)&lA[wm + i * 16 + r_lane][rd_col];
            bfr[i] = *(const bf16x8*)&lB[wn + i * 16 + r_lane][rd_col];
        }

#pragma unroll
        for (int i = 0; i < 4; i++)
#pragma unroll
            for (int j = 0; j < 4; j++)
                acc[i][j] = __builtin_amdgcn_mfma_f32_16x16x32_bf16(
                    af[i], bfr[j], acc[i][j], 0, 0, 0);

        __syncthreads();
    }

    const float s = *scale_p;
#pragma unroll
    for (int j = 0; j < 4; j++) {
        const int col  = n0 + wn + j * 16 + r_lane;
        const float bc = bias[col];
#pragma unroll
        for (int i = 0; i < 4; i++) {
            const int rowg = m0 + wm + i * 16 + quad * 4;
#pragma unroll
            for (int r = 0; r < 4; r++)
                Y[(size_t)(rowg + r) * N + col] = acc[i][j][r] * s + bc;
        }
    }
}

// ---------------- fallback: round-0 fused-convert kernel (unswizzled) ------
__global__ __launch_bounds__(256)
void ql_gemm_bf16_fused(const float* __restrict__ X, const float* __restrict__ W,
                        const float* __restrict__ bias, const float* __restrict__ scale_p,
                        float* __restrict__ Y, int M, int N, int K)
{
    __shared__ alignas(16) bf16_t lA[BM][BK];
    __shared__ alignas(16) bf16_t lB[BN][BK];

    const int tid  = threadIdx.x;
    const int lane = tid & 63;
    const int wave = tid >> 6;
    const int wm   = (wave & 1) * 64;
    const int wn   = (wave >> 1) * 64;
    const int m0 = blockIdx.x * BM;
    const int n0 = blockIdx.y * BN;
    const int r_lane = lane & 15;
    const int quad   = lane >> 4;

    f32x4 acc[4][4];
#pragma unroll
    for (int i = 0; i < 4; i++)
#pragma unroll
        for (int j = 0; j < 4; j++) acc[i][j] = (f32x4)0.0f;

    for (int k0 = 0; k0 < K; k0 += BK) {
#pragma unroll
        for (int i = 0; i < 4; i++) {
            const int l   = tid + i * 256;
            const int row = l >> 3;
            const int c4  = (l & 7) * 4;
            const float4 xa = *(const float4*)(X + (size_t)(m0 + row) * K + k0 + c4);
            const float4 wb = *(const float4*)(W + (size_t)(n0 + row) * K + k0 + c4);
            bf16x4 xh = { (bf16_t)xa.x, (bf16_t)xa.y, (bf16_t)xa.z, (bf16_t)xa.w };
            bf16x4 wh = { (bf16_t)wb.x, (bf16_t)wb.y, (bf16_t)wb.z, (bf16_t)wb.w };
            *(bf16x4*)&lA[row][c4] = xh;
            *(bf16x4*)&lB[row][c4] = wh;
        }
        __syncthreads();
        bf16x8 af[4], bfr[4];
#pragma unroll
        for (int i = 0; i < 4; i++) {
            af[i]  = *(const bf16x8*)&lA[wm + i * 16 + r_lane][quad * 8];
            bfr[i] = *(const bf16x8*)&lB[wn + i * 16 + r_lane][quad * 8];
        }
#pragma unroll
        for (int i = 0; i < 4; i++)
#pragma unroll
            for (int j = 0; j < 4; j++)
                acc[i][j] = __builtin_amdgcn_mfma_f32_16x16x32_bf16(af[i], bfr[j], acc[i][j], 0, 0, 0);
        __syncthreads();
    }

    const float s = *scale_p;
#pragma unroll
    for (int j = 0; j < 4; j++) {
        const int col  = n0 + wn + j * 16 + r_lane;
        const float bc = bias[col];
#pragma unroll
        for (int i = 0; i < 4; i++) {
            const int rowg = m0 + wm + i * 16 + quad * 4;
#pragma unroll
            for (int r = 0; r < 4; r++)
                Y[(size_t)(rowg + r) * N + col] = acc[i][j][r] * s + bc;
        }
    }
}

extern "C" void kernel_launch(void* const* d_in, const int* in_sizes, int n_in,
                              void* d_out, int out_size, void* d_ws, size_t ws_size,
                              hipStream_t stream) {
    const float* X     = (const float*)d_in[0];
    const float* W     = (const float*)d_in[1];
    const float* bias  = (const float*)d_in[2];
    const float* scale = (const float*)d_in[3];
    float* Y           = (float*)d_out;

    const int N = in_sizes[2];
    const int K = in_sizes[1] / N;
    const int M = in_sizes[0] / K;

    const size_t x_elems = (size_t)M * K;
    const size_t w_elems = (size_t)N * K;
    const size_t need = (x_elems + w_elems) * sizeof(bf16_t);

    dim3 grid(M / BM, N / BN);
    dim3 block(256);

    if (ws_size >= need) {
        bf16_t* Xb = (bf16_t*)d_ws;
        bf16_t* Wb = Xb + x_elems;
        long xn4 = (long)(x_elems / 4);
        long wn4 = (long)(w_elems / 4);
        long nthreads = xn4 + wn4;
        cvt2_f32_bf16<<<(nthreads + 255) / 256, 256, 0, stream>>>(X, Xb, xn4, W, Wb, wn4);
        ql_gemm_bf16_dma<<<grid, block, 0, stream>>>(Xb, Wb, bias, scale, Y, M, N, K);
    } else {
        ql_gemm_bf16_fused<<<grid, block, 0, stream>>>(X, W, bias, scale, Y, M, N, K);
    }
}